// Round 1
// baseline (118.773 us; speedup 1.0000x reference)
//
#include <hip/hip_runtime.h>

// Median blur 3x3 (kornia semantics) + fused mask copy.
// median commutes with monotone affine maps: 2*median((v+1)/2)-1 == median(v)
// with pad sentinel -1.0 (maps to reference's zero-pad in (v+1)/2 space).
//
// R9 = R8 with:
//  - 16-row bands (512 threads, 36 KB LDS, 4 blocks/CU): halo re-fetch
//    amplification 1.25x -> 1.125x on the image read stream.
//  - XCD-chunked block swizzle (bijective, 1536 % 8 == 0): vertically
//    adjacent bands of one plane stay on the same XCD L2 -> halo rows hit L2.
//  - non-temporal stores for image+mask outputs (never re-read; keep L2
//    for the halo reuse the swizzle creates).

#define W 512
#define H 512
#define PLANE (W * H)                 // 262144
#define NPLANES 48                    // 16 * 3
#define IMG_ELEMS (PLANE * NPLANES)   // 12582912
#define MASK_ELEMS (PLANE * 16)       // 4194304
#define MASK_F4 (MASK_ELEMS / 4)      // 1048576

#define ROWS 16                       // output rows per block
#define BANDS (H / ROWS)              // 32 bands per plane
#define MED_BLOCKS (NPLANES * BANDS)  // 1536
#define NTHREADS 512
#define MASK_PER_BLOCK ((MASK_F4 + MED_BLOCKS - 1) / MED_BLOCKS)  // 683
#define STAGE_ROWS (ROWS + 2)         // 18
#define STAGE_F4 (STAGE_ROWS * (W / 4))  // 2304

typedef float nfloat4 __attribute__((ext_vector_type(4)));

__device__ __forceinline__ float med3(float a, float b, float c) {
    return __builtin_amdgcn_fmed3f(a, b, c);
}
__device__ __forceinline__ float min3(float a, float b, float c) {
    return fminf(fminf(a, b), c);     // -> v_min3_f32
}
__device__ __forceinline__ float max3(float a, float b, float c) {
    return fmaxf(fmaxf(a, b), c);     // -> v_max3_f32
}

__global__ __launch_bounds__(NTHREADS) void fused_kernel(
        const float* __restrict__ img, const float* __restrict__ mask,
        float* __restrict__ out) {
    // XCD-chunked swizzle: hw round-robins blockIdx across the 8 XCDs;
    // remap so logical-consecutive bands share an XCD (halo rows L2-hit).
    // Bijective since MED_BLOCKS % 8 == 0.
    int b = blockIdx.x;
    int L = (b & 7) * (MED_BLOCKS / 8) + (b >> 3);

    // ---- mask slice for this block: issued first, overlaps everything ----
    {
        const nfloat4* src = (const nfloat4*)mask;
        nfloat4* dst = (nfloat4*)(out + IMG_ELEMS);
        int base = L * MASK_PER_BLOCK;
        int end = base + MASK_PER_BLOCK;
        if (end > MASK_F4) end = MASK_F4;
        #pragma unroll
        for (int k = 0; k < 2; ++k) {
            int j = base + (int)threadIdx.x + k * NTHREADS;
            if (j < end) {
                nfloat4 v = __builtin_nontemporal_load(&src[j]);
                __builtin_nontemporal_store(v, &dst[j]);
            }
        }
    }

    // ---- median path: block = plane p, 16 output rows starting at w*16 ----
    int p = L >> 5;               // 0..47
    int w = L & 31;               // 0..31
    int ybase = w << 4;           // first output row
    const float* plane = img + (size_t)p * PLANE;

    // Stage 18 input rows [ybase-1, ybase+17) into LDS; pad rows = -1.
    __shared__ float lds[STAGE_ROWS * W];     // 36 KB -> 4 blocks/CU
    {
        int y0m1 = ybase - 1;
        #pragma unroll
        for (int k = 0; k < 5; ++k) {
            int i = (int)threadIdx.x + k * NTHREADS;   // 0..2559
            if (i < STAGE_F4) {
                int r = i >> 7;                        // 0..17
                int c = (i & 127) << 2;                // 0..508
                int yy = y0m1 + r;
                nfloat4 v;
                if (yy >= 0 && yy < H) {
                    v = *(const nfloat4*)(plane + yy * W + c);
                } else {
                    v = (nfloat4){-1.0f, -1.0f, -1.0f, -1.0f};
                }
                *(nfloat4*)&lds[r * W + c] = v;
            }
        }
    }
    __syncthreads();

    // Compute: thread = (xseg 0..127, rb 0..3) -> 4 output rows x float4.
    int xseg = threadIdx.x & 127;
    int rb = threadIdx.x >> 7;            // 0..3
    int x0 = xseg << 2;                   // 0..508
    int lr = rb << 2;                     // local input-row base (rows lr..lr+5)
    float* outp = out + (size_t)p * PLANE + (size_t)(ybase + (rb << 2)) * W + x0;

    // Ring of 3 horizontally-sorted rows.
    float rl[3][4], rm[3][4], rh[3][4];

    #pragma unroll
    for (int r = 0; r < 6; ++r) {
        const float* row = &lds[(lr + r) * W];
        nfloat4 c = *(const nfloat4*)(row + x0);
        float tl = row[x0 > 0 ? x0 - 1 : 0];
        float tr = row[x0 + 4 < W ? x0 + 4 : W - 1];
        float t0 = (x0 > 0) ? tl : -1.0f;
        float t5 = (x0 + 4 < W) ? tr : -1.0f;
        float t1 = c.x, t2 = c.y, t3 = c.z, t4 = c.w;

        int s = r % 3;
        rl[s][0] = min3(t0, t1, t2); rm[s][0] = med3(t0, t1, t2); rh[s][0] = max3(t0, t1, t2);
        rl[s][1] = min3(t1, t2, t3); rm[s][1] = med3(t1, t2, t3); rh[s][1] = max3(t1, t2, t3);
        rl[s][2] = min3(t2, t3, t4); rm[s][2] = med3(t2, t3, t4); rh[s][2] = max3(t2, t3, t4);
        rl[s][3] = min3(t3, t4, t5); rm[s][3] = med3(t3, t4, t5); rh[s][3] = max3(t3, t4, t5);

        if (r >= 2) {
            int oy = r - 2;
            int s0 = oy % 3, s1 = (oy + 1) % 3, s2 = (oy + 2) % 3;
            nfloat4 o;
            #pragma unroll
            for (int k = 0; k < 4; ++k) {
                float mx = max3(rl[s0][k], rl[s1][k], rl[s2][k]);
                float md = med3(rm[s0][k], rm[s1][k], rm[s2][k]);
                float mn = min3(rh[s0][k], rh[s1][k], rh[s2][k]);
                o[k] = med3(mx, md, mn);
            }
            __builtin_nontemporal_store(o, (nfloat4*)(outp + oy * W));
        }
    }
}

extern "C" void kernel_launch(void* const* d_in, const int* in_sizes, int n_in,
                              void* d_out, int out_size, void* d_ws, size_t ws_size,
                              hipStream_t stream) {
    const float* img  = (const float*)d_in[0];
    const float* mask = (const float*)d_in[1];
    float* out = (float*)d_out;

    fused_kernel<<<MED_BLOCKS, NTHREADS, 0, stream>>>(img, mask, out);
}

// Round 2
// 117.378 us; speedup vs baseline: 1.0119x; 1.0119x over previous
//
#include <hip/hip_runtime.h>

// Median blur 3x3 (kornia semantics) + fused mask copy.
// median commutes with monotone affine maps: 2*median((v+1)/2)-1 == median(v)
// with pad sentinel -1.0 (maps to reference's zero-pad in (v+1)/2 space).
//
// R10 = R8 geometry (3072 blocks x 256 threads, 8-row bands) with the LDS
// stage DELETED: vertical reuse lives in a rolling register window, the
// +-1 horizontal neighbors are L1 hits (adjacent lanes of the same wave
// fetch those lines). Removes per-block barrier + vmcnt(0) drain + the
// whole LDS write/read round-trip. HBM traffic is compulsory either way
// (50 MB image streams through L2/L3 during the run; halo re-reads never
// reached HBM -- R9's lesson).

#define W 512
#define H 512
#define PLANE (W * H)                 // 262144
#define NPLANES 48                    // 16 * 3
#define IMG_ELEMS (PLANE * NPLANES)   // 12582912
#define MASK_ELEMS (PLANE * 16)       // 4194304
#define MASK_F4 (MASK_ELEMS / 4)      // 1048576
#define MED_BLOCKS (NPLANES * (H / 8))        // 3072 (64 blocks/plane)
#define MASK_PER_BLOCK 342            // ceil(1048576 / 3072)

typedef float nfloat4 __attribute__((ext_vector_type(4)));

__device__ __forceinline__ float med3(float a, float b, float c) {
    return __builtin_amdgcn_fmed3f(a, b, c);
}
__device__ __forceinline__ float min3(float a, float b, float c) {
    return fminf(fminf(a, b), c);     // -> v_min3_f32
}
__device__ __forceinline__ float max3(float a, float b, float c) {
    return fmaxf(fmaxf(a, b), c);     // -> v_max3_f32
}

__global__ __launch_bounds__(256) void fused_kernel(
        const float* __restrict__ img, const float* __restrict__ mask,
        float* __restrict__ out) {
    int b = blockIdx.x;

    // ---- mask slice for this block: issued first, overlaps everything ----
    {
        const nfloat4* src = (const nfloat4*)mask;
        nfloat4* dst = (nfloat4*)(out + IMG_ELEMS);
        int base = b * MASK_PER_BLOCK;
        int end = base + MASK_PER_BLOCK;
        if (end > MASK_F4) end = MASK_F4;
        #pragma unroll
        for (int k = 0; k < 2; ++k) {
            int j = base + (int)threadIdx.x + k * 256;
            if (j < end) dst[j] = src[j];
        }
    }

    // ---- median path: block = plane p, 8 output rows starting at w*8 ----
    int p = b >> 6;               // 0..47
    int w = b & 63;               // 0..63
    int xseg = threadIdx.x & 127;
    int rb = threadIdx.x >> 7;            // 0..1
    int x0 = xseg << 2;                   // 0..508
    int ybase = (w << 3) + (rb << 2);     // this thread's first output row
    const float* plane = img + (size_t)p * PLANE;
    float* outp = out + (size_t)p * PLANE + (size_t)ybase * W + x0;

    // Ring of 3 horizontally-sorted rows; input rows ybase-1 .. ybase+4
    // loaded DIRECTLY from global (coalesced dwordx4 + 2 L1-hit scalars).
    float rl[3][4], rm[3][4], rh[3][4];

    #pragma unroll
    for (int r = 0; r < 6; ++r) {
        int yy = ybase - 1 + r;
        float t0, t1, t2, t3, t4, t5;
        if (yy >= 0 && yy < H) {          // wave-uniform branch (yy same per wave)
            const float* row = plane + (size_t)yy * W;
            nfloat4 c = *(const nfloat4*)(row + x0);
            float tl = row[x0 > 0 ? x0 - 1 : 0];          // always in-bounds
            float tr = row[x0 + 4 < W ? x0 + 4 : W - 1];
            t0 = (x0 > 0) ? tl : -1.0f;
            t5 = (x0 + 4 < W) ? tr : -1.0f;
            t1 = c.x; t2 = c.y; t3 = c.z; t4 = c.w;
        } else {
            t0 = t1 = t2 = t3 = t4 = t5 = -1.0f;
        }

        int s = r % 3;
        rl[s][0] = min3(t0, t1, t2); rm[s][0] = med3(t0, t1, t2); rh[s][0] = max3(t0, t1, t2);
        rl[s][1] = min3(t1, t2, t3); rm[s][1] = med3(t1, t2, t3); rh[s][1] = max3(t1, t2, t3);
        rl[s][2] = min3(t2, t3, t4); rm[s][2] = med3(t2, t3, t4); rh[s][2] = max3(t2, t3, t4);
        rl[s][3] = min3(t3, t4, t5); rm[s][3] = med3(t3, t4, t5); rh[s][3] = max3(t3, t4, t5);

        if (r >= 2) {
            int oy = r - 2;
            int s0 = oy % 3, s1 = (oy + 1) % 3, s2 = (oy + 2) % 3;
            nfloat4 o;
            #pragma unroll
            for (int k = 0; k < 4; ++k) {
                float mx = max3(rl[s0][k], rl[s1][k], rl[s2][k]);
                float md = med3(rm[s0][k], rm[s1][k], rm[s2][k]);
                float mn = min3(rh[s0][k], rh[s1][k], rh[s2][k]);
                o[k] = med3(mx, md, mn);
            }
            *(nfloat4*)(outp + oy * W) = o;
        }
    }
}

extern "C" void kernel_launch(void* const* d_in, const int* in_sizes, int n_in,
                              void* d_out, int out_size, void* d_ws, size_t ws_size,
                              hipStream_t stream) {
    const float* img  = (const float*)d_in[0];
    const float* mask = (const float*)d_in[1];
    float* out = (float*)d_out;

    fused_kernel<<<MED_BLOCKS, 256, 0, stream>>>(img, mask, out);
}

// Round 3
// 113.441 us; speedup vs baseline: 1.0470x; 1.0347x over previous
//
#include <hip/hip_runtime.h>

// Median blur 3x3 (kornia semantics) + fused mask copy.
// median commutes with monotone affine maps: 2*median((v+1)/2)-1 == median(v)
// with pad sentinel -1.0 (maps to reference's zero-pad in (v+1)/2 space).
//
// R11 = R8 exactly (3072 x 256, 8-row bands, 20 KB LDS, fused mask slice)
// with ONE change: staging uses __builtin_amdgcn_global_load_lds width=16
// (direct HBM->LDS DMA, no VGPR round-trip; guide Common-mistake #1).
// Layout satisfies the DMA's wave-uniform-base + lane*16B requirement:
// within each 64-lane wave, r is uniform and c is lane-contiguous (16 B).
// Pad rows (wave-uniform oob) fall back to ds_write of -1.
// R9 lesson: halo re-reads never reach HBM (L2/L3 absorb them) -- keep 8-row
// bands. R10 lesson: per-thread global gather is worse than LDS staging.

#define W 512
#define H 512
#define PLANE (W * H)                 // 262144
#define NPLANES 48                    // 16 * 3
#define IMG_ELEMS (PLANE * NPLANES)   // 12582912
#define MASK_ELEMS (PLANE * 16)       // 4194304
#define MASK_F4 (MASK_ELEMS / 4)      // 1048576
#define MED_BLOCKS (NPLANES * (H / 8))        // 3072 (64 blocks/plane)
#define MASK_PER_BLOCK 342            // ceil(1048576 / 3072)

typedef float nfloat4 __attribute__((ext_vector_type(4)));

__device__ __forceinline__ float med3(float a, float b, float c) {
    return __builtin_amdgcn_fmed3f(a, b, c);
}
__device__ __forceinline__ float min3(float a, float b, float c) {
    return fminf(fminf(a, b), c);     // -> v_min3_f32
}
__device__ __forceinline__ float max3(float a, float b, float c) {
    return fmaxf(fmaxf(a, b), c);     // -> v_max3_f32
}

__global__ __launch_bounds__(256) void fused_kernel(
        const float* __restrict__ img, const float* __restrict__ mask,
        float* __restrict__ out) {
    int b = blockIdx.x;

    // ---- mask slice for this block: issued first, overlaps everything ----
    {
        const nfloat4* src = (const nfloat4*)mask;
        nfloat4* dst = (nfloat4*)(out + IMG_ELEMS);
        int base = b * MASK_PER_BLOCK;
        int end = base + MASK_PER_BLOCK;
        if (end > MASK_F4) end = MASK_F4;
        #pragma unroll
        for (int k = 0; k < 2; ++k) {
            int j = base + (int)threadIdx.x + k * 256;
            if (j < end) dst[j] = src[j];
        }
    }

    // ---- median path: block = plane p, 8 output rows starting at w*8 ----
    int p = b >> 6;               // 0..47
    int w = b & 63;               // 0..63
    int ybase = w << 3;           // first output row
    const float* plane = img + (size_t)p * PLANE;

    // Stage 10 input rows [ybase-1, ybase+9) into LDS; pad rows = -1.
    __shared__ float lds[10 * W];         // 20 KB -> 8 blocks/CU
    {
        int y0m1 = ybase - 1;
        #pragma unroll
        for (int k = 0; k < 5; ++k) {
            int i = (int)threadIdx.x + k * 256;   // 0..1279
            int r = i >> 7;                       // 0..9 (wave-uniform)
            int c = (i & 127) << 2;               // 0..508 (lane-contiguous *16B)
            int yy = y0m1 + r;                    // wave-uniform
            if (yy >= 0 && yy < H) {
                // Direct HBM->LDS DMA, 16 B/lane, no VGPR round-trip.
                __builtin_amdgcn_global_load_lds(
                    (const __attribute__((address_space(1))) unsigned int*)
                        (plane + (size_t)yy * W + c),
                    (__attribute__((address_space(3))) unsigned int*)
                        (&lds[r * W + c]),
                    16, 0, 0);
            } else {
                *(nfloat4*)&lds[r * W + c] =
                    (nfloat4){-1.0f, -1.0f, -1.0f, -1.0f};
            }
        }
    }
    __syncthreads();   // drains vmcnt (DMA completion) + lgkmcnt

    // Compute: thread = (xseg 0..127, rb 0..1) -> 4 output rows x float4.
    int xseg = threadIdx.x & 127;
    int rb = threadIdx.x >> 7;
    int x0 = xseg << 2;                   // 0..508
    int lr = rb << 2;                     // local input-row base (rows lr..lr+5)
    float* outp = out + (size_t)p * PLANE + (size_t)(ybase + (rb << 2)) * W + x0;

    // Ring of 3 horizontally-sorted rows.
    float rl[3][4], rm[3][4], rh[3][4];

    #pragma unroll
    for (int r = 0; r < 6; ++r) {
        const float* row = &lds[(lr + r) * W];
        nfloat4 c = *(const nfloat4*)(row + x0);
        float tl = row[x0 > 0 ? x0 - 1 : 0];
        float tr = row[x0 + 4 < W ? x0 + 4 : W - 1];
        float t0 = (x0 > 0) ? tl : -1.0f;
        float t5 = (x0 + 4 < W) ? tr : -1.0f;
        float t1 = c.x, t2 = c.y, t3 = c.z, t4 = c.w;

        int s = r % 3;
        rl[s][0] = min3(t0, t1, t2); rm[s][0] = med3(t0, t1, t2); rh[s][0] = max3(t0, t1, t2);
        rl[s][1] = min3(t1, t2, t3); rm[s][1] = med3(t1, t2, t3); rh[s][1] = max3(t1, t2, t3);
        rl[s][2] = min3(t2, t3, t4); rm[s][2] = med3(t2, t3, t4); rh[s][2] = max3(t2, t3, t4);
        rl[s][3] = min3(t3, t4, t5); rm[s][3] = med3(t3, t4, t5); rh[s][3] = max3(t3, t4, t5);

        if (r >= 2) {
            int oy = r - 2;
            int s0 = oy % 3, s1 = (oy + 1) % 3, s2 = (oy + 2) % 3;
            nfloat4 o;
            #pragma unroll
            for (int k = 0; k < 4; ++k) {
                float mx = max3(rl[s0][k], rl[s1][k], rl[s2][k]);
                float md = med3(rm[s0][k], rm[s1][k], rm[s2][k]);
                float mn = min3(rh[s0][k], rh[s1][k], rh[s2][k]);
                o[k] = med3(mx, md, mn);
            }
            *(nfloat4*)(outp + oy * W) = o;
        }
    }
}

extern "C" void kernel_launch(void* const* d_in, const int* in_sizes, int n_in,
                              void* d_out, int out_size, void* d_ws, size_t ws_size,
                              hipStream_t stream) {
    const float* img  = (const float*)d_in[0];
    const float* mask = (const float*)d_in[1];
    float* out = (float*)d_out;

    fused_kernel<<<MED_BLOCKS, 256, 0, stream>>>(img, mask, out);
}